// Round 2
// 974.090 us; speedup vs baseline: 1.0316x; 1.0316x over previous
//
#include <hip/hip_runtime.h>

typedef unsigned int u32;
typedef unsigned short u16;
typedef __attribute__((ext_vector_type(8))) short short8;
typedef __attribute__((ext_vector_type(8))) unsigned short ushort8v;
typedef __attribute__((ext_vector_type(4))) unsigned short ushort4v;
typedef __attribute__((ext_vector_type(4))) float f32x4;

#define NSRC 50000
#define NTGT 50000
#define NEDGE 640000
#define LDIM 128
#define SLOPE 0.01f

#define MFMA(a, b, c) __builtin_amdgcn_mfma_f32_16x16x32_bf16((a), (b), (c), 0, 0, 0)

// ---------- helpers ----------
__device__ __forceinline__ u16 f2bf(float f) {
  union { float f; u32 u; } v; v.f = f;
  u32 r = v.u + 0x7FFFu + ((v.u >> 16) & 1u);   // RNE
  return (u16)(r >> 16);
}
__device__ __forceinline__ float bf2f(u16 h) {
  union { u32 u; float f; } v; v.u = ((u32)h) << 16; return v.f;
}

// ---------- W2B = W2 @ U1[128:384]  (f32, [256][512]) ----------
__global__ void k_w2b(const float* __restrict__ W2, const float* __restrict__ U1,
                      float* __restrict__ w2b) {
  const int i = blockIdx.x;       // 256 rows
  const int j = threadIdx.x;      // 256 threads, 2 cols each
  const float* __restrict__ u = U1 + (size_t)128 * 512;
  float a0 = 0.f, a1 = 0.f;
#pragma unroll 8
  for (int k = 0; k < 256; ++k) {
    float w = W2[(size_t)i * 256 + k];
    a0 += w * u[(size_t)k * 512 + j];
    a1 += w * u[(size_t)k * 512 + j + 256];
  }
  w2b[(size_t)i * 512 + j] = a0;
  w2b[(size_t)i * 512 + j + 256] = a1;
}

// ---------- c1e = c1 + xu @ U1[384:512] ;  vb = b2 @ U1[128:384] ----------
__global__ void k_bias(const float* __restrict__ U1, const float* __restrict__ xu,
                       const float* __restrict__ b2, const float* __restrict__ c1,
                       float* __restrict__ c1e, float* __restrict__ vb) {
  const int j = threadIdx.x;      // 512
  float s = c1[j];
#pragma unroll 4
  for (int k = 0; k < 128; ++k) s += xu[k] * U1[(size_t)(384 + k) * 512 + j];
  float v = 0.f;
#pragma unroll 4
  for (int k = 0; k < 256; ++k) v += b2[k] * U1[(size_t)(128 + k) * 512 + j];
  c1e[j] = s;
  vb[j] = v;
}

// ---------- weight prep: pack to bf16 fragment-linear ----------
// pack[(g*64 + lane)*8 + j] = W[kc*32 + (lane>>4)*8 + j][cb*16 + (lane&15)]
__global__ void k_prep(const float* __restrict__ W1, const float* __restrict__ U1,
                       const float* __restrict__ U2, const float* __restrict__ w2b,
                       u16* __restrict__ w1a, u16* __restrict__ w1b,
                       u16* __restrict__ u1e, u16* __restrict__ u2p) {
  int id = blockIdx.x * 256 + threadIdx.x;
  int lane = id & 63, quad = (lane >> 4), l16 = lane & 15;
  if (id < 4096) {                      // W1a: rows 0..127 of W1, N=256, 4 kc x 16 cb
    int g = id >> 6;
    int kc = g >> 4, cb = g & 15;
    const float* s = W1 + (size_t)(kc * 32 + quad * 8) * 256 + cb * 16 + l16;
    ushort8v p;
#pragma unroll
    for (int j = 0; j < 8; ++j) p[j] = f2bf(s[(size_t)j * 256]);
    *(ushort8v*)(w1a + ((size_t)g * 64 + lane) * 8) = p;
  } else if (id < 8192) {               // W1b: rows 128..255 of W1
    int g = (id - 4096) >> 6;
    int kc = g >> 4, cb = g & 15;
    const float* s = W1 + (size_t)(128 + kc * 32 + quad * 8) * 256 + cb * 16 + l16;
    ushort8v p;
#pragma unroll
    for (int j = 0; j < 8; ++j) p[j] = f2bf(s[(size_t)j * 256]);
    *(ushort8v*)(w1b + ((size_t)g * 64 + lane) * 8) = p;
  } else if (id < 32768) {              // U1eff: [U1[0:128]; W2B], K=384, N=512, 12 kc x 32 cb
    int g = (id - 8192) >> 6;
    int kc = g >> 5, cb = g & 31;
    int col = cb * 16 + l16;
    ushort8v p;
#pragma unroll
    for (int j = 0; j < 8; ++j) {
      int row = kc * 32 + quad * 8 + j;
      float v = (row < 128) ? U1[(size_t)row * 512 + col]
                            : w2b[(size_t)(row - 128) * 512 + col];
      p[j] = f2bf(v);
    }
    *(ushort8v*)(u1e + ((size_t)g * 64 + lane) * 8) = p;
  } else if (id < 40960) {              // U2: K=512, N=128, 16 kc x 8 cb
    int g = (id - 32768) >> 6;
    int kc = g >> 3, cb = g & 7;
    const float* s = U2 + (size_t)(kc * 32 + quad * 8) * 128 + cb * 16 + l16;
    ushort8v p;
#pragma unroll
    for (int j = 0; j < 8; ++j) p[j] = f2bf(s[(size_t)j * 128]);
    *(ushort8v*)(u2p + ((size_t)g * 64 + lane) * 8) = p;
  }
}

// ---------- counting sort by target ----------
__global__ void k_count(const int* __restrict__ tgt, int* __restrict__ cnt,
                        int* __restrict__ rank) {
  int e = blockIdx.x * 256 + threadIdx.x;
  if (e < NEDGE) rank[e] = atomicAdd(&cnt[tgt[e]], 1);
}

__global__ void k_scan(const int* __restrict__ cnt, int* __restrict__ rowstart) {
  __shared__ int part[1024];
  int tid = threadIdx.x;
  int base = tid * 49;                       // 1024*49 = 50176 >= 50000
  int s = 0;
  for (int i = 0; i < 49; ++i) { int idx = base + i; if (idx < NTGT) s += cnt[idx]; }
  part[tid] = s;
  __syncthreads();
  for (int off = 1; off < 1024; off <<= 1) {
    int v = (tid >= off) ? part[tid - off] : 0;
    __syncthreads();
    part[tid] += v;
    __syncthreads();
  }
  int run = (tid > 0) ? part[tid - 1] : 0;
  for (int i = 0; i < 49; ++i) {
    int idx = base + i;
    if (idx < NTGT) { rowstart[idx] = run; run += cnt[idx]; }
  }
  if (tid == 1023) rowstart[NTGT] = part[1023];
}

__global__ void k_pos(const int* __restrict__ tgt, const int* __restrict__ rowstart,
                      int* __restrict__ pos) {
  int e = blockIdx.x * 256 + threadIdx.x;
  if (e < NEDGE) pos[e] = rowstart[tgt[e]] + pos[e];   // pos aliases rank
}

// ---------- P = bf16(x_s @ W1a + b1), [NSRC][256] ----------
__global__ __launch_bounds__(256, 3) void k_pgemm(
    const float* __restrict__ xs, const u16* __restrict__ w1ap,
    const float* __restrict__ b1, u16* __restrict__ P) {
  __shared__ u16 At[64][136];    // 17408 B
  __shared__ u16 Ot[64][264];    // 33792 B
  const int tid = threadIdx.x;
  const int base = blockIdx.x * 64;
  {
    const int et = tid >> 2, p = tid & 3;
    const int row = base + et;
    u16* dst = &At[et][p * 32];
    if (row < NSRC) {
      const float4* f4 = (const float4*)(xs + (size_t)row * LDIM + p * 32);
#pragma unroll
      for (int i = 0; i < 4; ++i) {
        float4 a = f4[2 * i], b = f4[2 * i + 1];
        ushort8v pk = { f2bf(a.x), f2bf(a.y), f2bf(a.z), f2bf(a.w),
                        f2bf(b.x), f2bf(b.y), f2bf(b.z), f2bf(b.w) };
        *(ushort8v*)(dst + i * 8) = pk;
      }
    } else {
      ushort8v z = {0, 0, 0, 0, 0, 0, 0, 0};
#pragma unroll
      for (int i = 0; i < 4; ++i) *(ushort8v*)(dst + i * 8) = z;
    }
  }
  __syncthreads();

  const int lane = tid & 63, wid = tid >> 6;
  const int quad = lane >> 4, l16 = lane & 15;
  const int colb = wid * 64;
  const short8* __restrict__ wf = (const short8*)w1ap;

  f32x4 acc[4][4];
#pragma unroll
  for (int a = 0; a < 4; ++a)
#pragma unroll
    for (int b = 0; b < 4; ++b) acc[a][b] = (f32x4){0.f, 0.f, 0.f, 0.f};
#pragma unroll
  for (int kc = 0; kc < 4; ++kc) {
    short8 af[4], bfr[4];
#pragma unroll
    for (int ct = 0; ct < 4; ++ct)
      bfr[ct] = wf[(size_t)(kc * 16 + wid * 4 + ct) * 64 + lane];
#pragma unroll
    for (int rt = 0; rt < 4; ++rt)
      af[rt] = *(const short8*)&At[rt * 16 + l16][kc * 32 + quad * 8];
#pragma unroll
    for (int rt = 0; rt < 4; ++rt)
#pragma unroll
      for (int ct = 0; ct < 4; ++ct)
        acc[rt][ct] = MFMA(af[rt], bfr[ct], acc[rt][ct]);
  }
  // epilogue: + b1, store bf16 (NO activation: P is pre-activation partial)
#pragma unroll
  for (int ct = 0; ct < 4; ++ct) {
    int col = colb + ct * 16 + l16;
    float bias = b1[col];
#pragma unroll
    for (int rt = 0; rt < 4; ++rt)
#pragma unroll
      for (int r = 0; r < 4; ++r) {
        int row = rt * 16 + quad * 4 + r;
        Ot[row][col] = f2bf(acc[rt][ct][r] + bias);
      }
  }
  __syncthreads();
  {
    const int et = tid >> 2, p = tid & 3;
    const int row = base + et;
    if (row < NSRC) {
      u16* dst = P + (size_t)row * 256 + p * 64;
      const u16* sl = &Ot[et][p * 64];
#pragma unroll
      for (int i = 0; i < 8; ++i)
        *(ushort8v*)(dst + i * 8) = *(const ushort8v*)(sl + i * 8);
    }
  }
}

// ---------- edge: t = leaky(P[src] + ea @ W1b), K=128, one GEMM, 2 barriers ----------
__global__ __launch_bounds__(256, 3) void k_edge(
    const float* __restrict__ ea, const int* __restrict__ srcp,
    const u16* __restrict__ Pg, const u16* __restrict__ w1bp,
    const int* __restrict__ pos, u16* __restrict__ tbuf) {
  __shared__ u16 At[64][136];    // ea tile, 17408 B
  __shared__ u16 Pt[64][264];    // P gather, then t output, 33792 B
  const int tid = threadIdx.x;
  const int ebase = blockIdx.x * 64;

  {
    const int et = tid >> 2, p = tid & 3;
    if (p < 2) {
      const float4* f4 = (const float4*)(ea + (size_t)(ebase + et) * LDIM + p * 64);
      u16* dst = &At[et][p * 64];
#pragma unroll
      for (int i = 0; i < 8; ++i) {
        float4 a = f4[2 * i], b = f4[2 * i + 1];
        ushort8v pk = { f2bf(a.x), f2bf(a.y), f2bf(a.z), f2bf(a.w),
                        f2bf(b.x), f2bf(b.y), f2bf(b.z), f2bf(b.w) };
        *(ushort8v*)(dst + i * 8) = pk;
      }
    } else {
      int sidx = srcp[ebase + et];
      const ushort8v* pr = (const ushort8v*)(Pg + (size_t)sidx * 256 + (p - 2) * 128);
      u16* dst = &Pt[et][(p - 2) * 128];
#pragma unroll
      for (int i = 0; i < 16; ++i) *(ushort8v*)(dst + i * 8) = pr[i];
    }
  }
  __syncthreads();

  const int lane = tid & 63, wid = tid >> 6;
  const int quad = lane >> 4, l16 = lane & 15;
  const int colb = wid * 64;
  const short8* __restrict__ wf = (const short8*)w1bp;

  f32x4 acc[4][4];
#pragma unroll
  for (int a = 0; a < 4; ++a)
#pragma unroll
    for (int b = 0; b < 4; ++b) acc[a][b] = (f32x4){0.f, 0.f, 0.f, 0.f};
#pragma unroll
  for (int kc = 0; kc < 4; ++kc) {
    short8 af[4], bfr[4];
#pragma unroll
    for (int ct = 0; ct < 4; ++ct)
      bfr[ct] = wf[(size_t)(kc * 16 + wid * 4 + ct) * 64 + lane];
#pragma unroll
    for (int rt = 0; rt < 4; ++rt)
      af[rt] = *(const short8*)&At[rt * 16 + l16][kc * 32 + quad * 8];
#pragma unroll
    for (int rt = 0; rt < 4; ++rt)
#pragma unroll
      for (int ct = 0; ct < 4; ++ct)
        acc[rt][ct] = MFMA(af[rt], bfr[ct], acc[rt][ct]);
  }
  // epilogue: + P (per wave's own column block), leaky, write t in-place
#pragma unroll
  for (int ct = 0; ct < 4; ++ct) {
    int col = colb + ct * 16 + l16;
#pragma unroll
    for (int rt = 0; rt < 4; ++rt)
#pragma unroll
      for (int r = 0; r < 4; ++r) {
        int row = rt * 16 + quad * 4 + r;
        float v = acc[rt][ct][r] + bf2f(Pt[row][col]);
        v = v > 0.f ? v : SLOPE * v;
        Pt[row][col] = f2bf(v);
      }
  }
  __syncthreads();

  {
    const int et = tid >> 2, p = tid & 3;
    const int gp = pos[ebase + et];
    u16* dst = tbuf + (size_t)gp * 256 + p * 64;
    const u16* sl = &Pt[et][p * 64];
#pragma unroll
    for (int i = 0; i < 8; ++i)
      *(ushort8v*)(dst + i * 8) = *(const ushort8v*)(sl + i * 8);
  }
}

// ---------- node update: ain = [x_t | T], K=384 GEMM1 with folded U1eff ----------
__global__ __launch_bounds__(256, 4) void k_node(
    const float* __restrict__ xt, const u16* __restrict__ tbuf,
    const int* __restrict__ rowstart, const u16* __restrict__ u1e,
    const u16* __restrict__ u2p, const float* __restrict__ c1e,
    const float* __restrict__ vb, const float* __restrict__ c2,
    float* __restrict__ h2, float* __restrict__ stats) {
  __shared__ u16 ain[32][520];   // 33280 B
  __shared__ float sdeg[32];
  const int tid = threadIdx.x;
  const int lane = tid & 63, wid = tid >> 6;
  const int quad = lane >> 4, l16 = lane & 15;
  const int tbase = blockIdx.x * 32;

  // ---- stage: one wave per target slot ----
  for (int s = wid; s < 32; s += 4) {
    int t = tbase + s;
    if (t < NTGT) {
      if (lane < 32) {
        float4 v = ((const float4*)(xt + (size_t)t * LDIM))[lane];
        ushort4v p = { f2bf(v.x), f2bf(v.y), f2bf(v.z), f2bf(v.w) };
        *(ushort4v*)&ain[s][lane * 4] = p;
      }
      int rs = rowstart[t], re = rowstart[t + 1];
      if (lane == 0) sdeg[s] = (float)(re - rs);
      float acc8[8] = {0.f, 0.f, 0.f, 0.f, 0.f, 0.f, 0.f, 0.f};
      const u16* mb = tbuf + ((size_t)rs + (lane >> 5)) * 256 + (lane & 31) * 8;
      int n = re - rs, nfull = n & ~1;
      for (int r = 0; r < nfull; r += 2) {
        ushort8v m = *(const ushort8v*)(mb + (size_t)r * 256);
#pragma unroll
        for (int j = 0; j < 8; ++j) acc8[j] += bf2f(m[j]);
      }
      if (n & 1) {
        if (lane < 32) {
          ushort8v m = *(const ushort8v*)(tbuf + (size_t)(re - 1) * 256 + lane * 8);
#pragma unroll
          for (int j = 0; j < 8; ++j) acc8[j] += bf2f(m[j]);
        }
      }
#pragma unroll
      for (int j = 0; j < 8; ++j) acc8[j] += __shfl_down(acc8[j], 32);
      if (lane < 32) {
        ushort8v p;
#pragma unroll
        for (int j = 0; j < 8; ++j) p[j] = f2bf(acc8[j]);
        *(ushort8v*)&ain[s][128 + lane * 8] = p;
      }
    } else {
      ushort8v z = {0, 0, 0, 0, 0, 0, 0, 0};
      *(ushort8v*)&ain[s][lane * 8] = z;
      if (lane == 0) sdeg[s] = 0.f;
    }
  }
  __syncthreads();

  const short8* __restrict__ u1f = (const short8*)u1e;
  const short8* __restrict__ u2f = (const short8*)u2p;

  // ---- GEMM1: h1 = leaky([x_t|T] @ U1eff + c1e + deg*vb), K=384, N=512 ----
  f32x4 acc[2][2][4];   // [half][rowtile][coltile]
#pragma unroll
  for (int h = 0; h < 2; ++h)
#pragma unroll
    for (int a = 0; a < 2; ++a)
#pragma unroll
      for (int b = 0; b < 4; ++b) acc[h][a][b] = (f32x4){0.f, 0.f, 0.f, 0.f};

#pragma unroll 2
  for (int kc = 0; kc < 12; ++kc) {
    short8 af[2];
#pragma unroll
    for (int rt = 0; rt < 2; ++rt)
      af[rt] = *(const short8*)&ain[rt * 16 + l16][kc * 32 + quad * 8];
#pragma unroll
    for (int h = 0; h < 2; ++h) {
      short8 bfr[4];
#pragma unroll
      for (int ct = 0; ct < 4; ++ct)
        bfr[ct] = u1f[(size_t)(kc * 32 + h * 16 + wid * 4 + ct) * 64 + lane];
#pragma unroll
      for (int rt = 0; rt < 2; ++rt)
#pragma unroll
        for (int ct = 0; ct < 4; ++ct)
          acc[h][rt][ct] = MFMA(af[rt], bfr[ct], acc[h][rt][ct]);
    }
  }
  __syncthreads();
  // epilogue 1 -> ain (h1, bf16)
#pragma unroll
  for (int h = 0; h < 2; ++h)
#pragma unroll
    for (int ct = 0; ct < 4; ++ct) {
      int col = h * 256 + wid * 64 + ct * 16 + l16;
      float cb = c1e[col], vbb = vb[col];
#pragma unroll
      for (int rt = 0; rt < 2; ++rt)
#pragma unroll
        for (int r = 0; r < 4; ++r) {
          int row = rt * 16 + quad * 4 + r;
          float v = acc[h][rt][ct][r] + cb + sdeg[row] * vbb;
          v = v > 0.f ? v : SLOPE * v;
          ain[row][col] = f2bf(v);
        }
    }
  __syncthreads();

  // ---- GEMM2: h2 = h1 @ U2 + c2, K=512, N=128 ----
  const int colb2 = wid * 32;
  f32x4 acc2[2][2];
#pragma unroll
  for (int a = 0; a < 2; ++a)
#pragma unroll
    for (int b = 0; b < 2; ++b) acc2[a][b] = (f32x4){0.f, 0.f, 0.f, 0.f};
#pragma unroll 4
  for (int kc = 0; kc < 16; ++kc) {
    short8 af[2], bfr[2];
#pragma unroll
    for (int ct = 0; ct < 2; ++ct)
      bfr[ct] = u2f[(size_t)(kc * 8 + wid * 2 + ct) * 64 + lane];
#pragma unroll
    for (int rt = 0; rt < 2; ++rt)
      af[rt] = *(const short8*)&ain[rt * 16 + l16][kc * 32 + quad * 8];
#pragma unroll
    for (int rt = 0; rt < 2; ++rt)
#pragma unroll
      for (int ct = 0; ct < 2; ++ct)
        acc2[rt][ct] = MFMA(af[rt], bfr[ct], acc2[rt][ct]);
  }
  // ---- epilogue 2: store h2 (f32) + BN partial sums ----
  float s1[2] = {0.f, 0.f}, s2[2] = {0.f, 0.f};
#pragma unroll
  for (int ct = 0; ct < 2; ++ct) {
    int col = colb2 + ct * 16 + l16;
    float cb = c2[col];
#pragma unroll
    for (int rt = 0; rt < 2; ++rt)
#pragma unroll
      for (int r = 0; r < 4; ++r) {
        int row = rt * 16 + quad * 4 + r;
        int t = tbase + row;
        if (t < NTGT) {
          float v = acc2[rt][ct][r] + cb;
          h2[(size_t)t * LDIM + col] = v;
          s1[ct] += v; s2[ct] += v * v;
        }
      }
  }
#pragma unroll
  for (int ct = 0; ct < 2; ++ct) {
    float a = s1[ct], b = s2[ct];
    a += __shfl_down(a, 32); b += __shfl_down(b, 32);
    a += __shfl_down(a, 16); b += __shfl_down(b, 16);
    if (lane < 16) {
      atomicAdd(&stats[colb2 + ct * 16 + l16], a);
      atomicAdd(&stats[128 + colb2 + ct * 16 + l16], b);
    }
  }
}

// ---------- BN finalize + apply ----------
__global__ void k_bnfin(const float* __restrict__ stats, const float* __restrict__ gamma,
                        const float* __restrict__ beta, float* __restrict__ ss) {
  int c = threadIdx.x;
  if (c < 128) {
    float mu = stats[c] * (1.0f / NTGT);
    float var = stats[128 + c] * (1.0f / NTGT) - mu * mu;
    float rs = rsqrtf(var + 1e-5f);
    float sc = gamma[c] * rs;
    ss[c] = sc;
    ss[128 + c] = beta[c] - mu * sc;
  }
}

__global__ void k_bnapply(const float* __restrict__ h2, const float* __restrict__ ss,
                          float* __restrict__ out) {
  int i = blockIdx.x * 256 + threadIdx.x;
  const int total = NTGT * LDIM / 4;
  const float4* h4 = (const float4*)h2;
  const float4* sc4 = (const float4*)ss;
  const float4* sh4 = (const float4*)(ss + 128);
  float4* o4 = (float4*)out;
  for (; i < total; i += gridDim.x * 256) {
    int cg = i & 31;
    float4 h = h4[i], sc = sc4[cg], sh = sh4[cg];
    float4 r = { h.x * sc.x + sh.x, h.y * sc.y + sh.y,
                 h.z * sc.z + sh.z, h.w * sc.w + sh.w };
    o4[i] = r;
  }
}

// ---------- launch ----------
extern "C" void kernel_launch(void* const* d_in, const int* in_sizes, int n_in,
                              void* d_out, int out_size, void* d_ws, size_t ws_size,
                              hipStream_t stream) {
  (void)in_sizes; (void)n_in; (void)out_size; (void)ws_size;
  const float* xs    = (const float*)d_in[0];
  const float* xt    = (const float*)d_in[1];
  const int*   ei    = (const int*)d_in[2];
  const float* ea    = (const float*)d_in[3];
  const float* xu    = (const float*)d_in[4];
  const float* W1    = (const float*)d_in[5];
  const float* b1    = (const float*)d_in[6];
  const float* W2    = (const float*)d_in[7];
  const float* b2    = (const float*)d_in[8];
  const float* U1    = (const float*)d_in[9];
  const float* c1    = (const float*)d_in[10];
  const float* U2    = (const float*)d_in[11];
  const float* c2    = (const float*)d_in[12];
  const float* gamma = (const float*)d_in[13];
  const float* beta  = (const float*)d_in[14];

  char* ws = (char*)d_ws;
  u16* w1a   = (u16*)(ws + 0x000000);     // 65536 B
  u16* w1b   = (u16*)(ws + 0x010000);     // 65536 B
  u16* u1e   = (u16*)(ws + 0x020000);     // 393216 B  (ends 0x80000)
  u16* u2p   = (u16*)(ws + 0x080000);     // 131072 B  (ends 0xA0000)
  float* w2b = (float*)(ws + 0x0A0000);   // 524288 B  (ends 0x120000)
  float* c1e = (float*)(ws + 0x120000);   // 2048 B
  float* vbv = (float*)(ws + 0x120800);   // 2048 B
  int* cnt   = (int*)(ws + 0x130000);     // 200000 B  (ends 0x160D40)
  int* rowst = (int*)(ws + 0x161000);     // 200004 B  (ends 0x191D44)
  int* pos   = (int*)(ws + 0x192000);     // 2560000 B (ends 0x403000)
  float* stats = (float*)(ws + 0x410000); // colsum[128] | colsq[128]  (1024 B)
  float* ss    = stats + 256;             // scale[128] | shift[128]   (1024 B)
  // P (u16 [NSRC][256], 25.6 MB) aliases h2 (f32 [NTGT][128], 25.6 MB):
  // P is dead after k_edge; h2 first written by k_node (same stream, later).
  // [0x412000, 0x412000+25600000) = [0x412000, 0x1C7C800) — clear of tbuf.
  u16*   Pbuf = (u16*)(ws + 0x412000);    // 25600000 B
  float* h2   = (float*)(ws + 0x412000);
  u16*   tbuf = (u16*)(ws + 0x1C80000);   // 327680000 B (sorted t rows, bf16)

  const int* srcp = ei;
  const int* tgtp = ei + NEDGE;

  hipMemsetAsync(cnt, 0, NTGT * 4, stream);
  hipMemsetAsync(stats, 0, 256 * 4, stream);
  k_w2b<<<256, 256, 0, stream>>>(W2, U1, w2b);
  k_bias<<<1, 512, 0, stream>>>(U1, xu, b2, c1, c1e, vbv);
  k_prep<<<160, 256, 0, stream>>>(W1, U1, U2, w2b, w1a, w1b, u1e, u2p);
  k_count<<<2500, 256, 0, stream>>>(tgtp, cnt, pos);
  k_scan<<<1, 1024, 0, stream>>>(cnt, rowst);
  k_pos<<<2500, 256, 0, stream>>>(tgtp, rowst, pos);
  k_pgemm<<<782, 256, 0, stream>>>(xs, w1a, b1, Pbuf);
  k_edge<<<10000, 256, 0, stream>>>(ea, srcp, Pbuf, w1b, pos, tbuf);
  k_node<<<1563, 256, 0, stream>>>(xt, tbuf, rowst, u1e, u2p, c1e, vbv, c2, h2, stats);
  k_bnfin<<<1, 128, 0, stream>>>(stats, gamma, beta, ss);
  k_bnapply<<<6250, 256, 0, stream>>>(h2, ss, (float*)d_out);
}

// Round 3
// 905.063 us; speedup vs baseline: 1.1103x; 1.0763x over previous
//
#include <hip/hip_runtime.h>

typedef unsigned int u32;
typedef unsigned short u16;
typedef __attribute__((ext_vector_type(8))) short short8;
typedef __attribute__((ext_vector_type(8))) unsigned short ushort8v;
typedef __attribute__((ext_vector_type(4))) unsigned short ushort4v;
typedef __attribute__((ext_vector_type(4))) float f32x4;

#define NSRC 50000
#define NTGT 50000
#define NEDGE 640000
#define LDIM 128
#define SLOPE 0.01f

#define MFMA(a, b, c) __builtin_amdgcn_mfma_f32_16x16x32_bf16((a), (b), (c), 0, 0, 0)

// ---------- helpers ----------
__device__ __forceinline__ u16 f2bf(float f) {
  union { float f; u32 u; } v; v.f = f;
  u32 r = v.u + 0x7FFFu + ((v.u >> 16) & 1u);   // RNE
  return (u16)(r >> 16);
}
__device__ __forceinline__ float bf2f(u16 h) {
  union { u32 u; float f; } v; v.u = ((u32)h) << 16; return v.f;
}

// ---------- W2B = W2 @ U1[128:384]  (f32, [256][512]) ----------
__global__ void k_w2b(const float* __restrict__ W2, const float* __restrict__ U1,
                      float* __restrict__ w2b) {
  const int i = blockIdx.x;       // 256 rows
  const int j = threadIdx.x;      // 256 threads, 2 cols each
  const float* __restrict__ u = U1 + (size_t)128 * 512;
  float a0 = 0.f, a1 = 0.f;
#pragma unroll 8
  for (int k = 0; k < 256; ++k) {
    float w = W2[(size_t)i * 256 + k];
    a0 += w * u[(size_t)k * 512 + j];
    a1 += w * u[(size_t)k * 512 + j + 256];
  }
  w2b[(size_t)i * 512 + j] = a0;
  w2b[(size_t)i * 512 + j + 256] = a1;
}

// ---------- c1e = c1 + xu @ U1[384:512] ;  vb = b2 @ U1[128:384] ----------
__global__ void k_bias(const float* __restrict__ U1, const float* __restrict__ xu,
                       const float* __restrict__ b2, const float* __restrict__ c1,
                       float* __restrict__ c1e, float* __restrict__ vb) {
  const int j = threadIdx.x;      // 512
  float s = c1[j];
#pragma unroll 4
  for (int k = 0; k < 128; ++k) s += xu[k] * U1[(size_t)(384 + k) * 512 + j];
  float v = 0.f;
#pragma unroll 4
  for (int k = 0; k < 256; ++k) v += b2[k] * U1[(size_t)(128 + k) * 512 + j];
  c1e[j] = s;
  vb[j] = v;
}

// ---------- weight prep: pack to bf16 fragment-linear ----------
// pack[(g*64 + lane)*8 + j] = W[kc*32 + (lane>>4)*8 + j][cb*16 + (lane&15)]
__global__ void k_prep(const float* __restrict__ W1, const float* __restrict__ U1,
                       const float* __restrict__ U2, const float* __restrict__ w2b,
                       u16* __restrict__ w1a, u16* __restrict__ w1b,
                       u16* __restrict__ u1e, u16* __restrict__ u2p) {
  int id = blockIdx.x * 256 + threadIdx.x;
  int lane = id & 63, quad = (lane >> 4), l16 = lane & 15;
  if (id < 4096) {                      // W1a: rows 0..127 of W1, N=256, 4 kc x 16 cb
    int g = id >> 6;
    int kc = g >> 4, cb = g & 15;
    const float* s = W1 + (size_t)(kc * 32 + quad * 8) * 256 + cb * 16 + l16;
    ushort8v p;
#pragma unroll
    for (int j = 0; j < 8; ++j) p[j] = f2bf(s[(size_t)j * 256]);
    *(ushort8v*)(w1a + ((size_t)g * 64 + lane) * 8) = p;
  } else if (id < 8192) {               // W1b: rows 128..255 of W1
    int g = (id - 4096) >> 6;
    int kc = g >> 4, cb = g & 15;
    const float* s = W1 + (size_t)(128 + kc * 32 + quad * 8) * 256 + cb * 16 + l16;
    ushort8v p;
#pragma unroll
    for (int j = 0; j < 8; ++j) p[j] = f2bf(s[(size_t)j * 256]);
    *(ushort8v*)(w1b + ((size_t)g * 64 + lane) * 8) = p;
  } else if (id < 32768) {              // U1eff: [U1[0:128]; W2B], K=384, N=512, 12 kc x 32 cb
    int g = (id - 8192) >> 6;
    int kc = g >> 5, cb = g & 31;
    int col = cb * 16 + l16;
    ushort8v p;
#pragma unroll
    for (int j = 0; j < 8; ++j) {
      int row = kc * 32 + quad * 8 + j;
      float v = (row < 128) ? U1[(size_t)row * 512 + col]
                            : w2b[(size_t)(row - 128) * 512 + col];
      p[j] = f2bf(v);
    }
    *(ushort8v*)(u1e + ((size_t)g * 64 + lane) * 8) = p;
  } else if (id < 40960) {              // U2: K=512, N=128, 16 kc x 8 cb
    int g = (id - 32768) >> 6;
    int kc = g >> 3, cb = g & 7;
    const float* s = U2 + (size_t)(kc * 32 + quad * 8) * 128 + cb * 16 + l16;
    ushort8v p;
#pragma unroll
    for (int j = 0; j < 8; ++j) p[j] = f2bf(s[(size_t)j * 128]);
    *(ushort8v*)(u2p + ((size_t)g * 64 + lane) * 8) = p;
  }
}

// ---------- counting sort by target ----------
__global__ void k_count(const int* __restrict__ tgt, int* __restrict__ cnt,
                        int* __restrict__ rank) {
  int e = blockIdx.x * 256 + threadIdx.x;
  if (e < NEDGE) rank[e] = atomicAdd(&cnt[tgt[e]], 1);
}

__global__ void k_scan(const int* __restrict__ cnt, int* __restrict__ rowstart) {
  __shared__ int part[1024];
  int tid = threadIdx.x;
  int base = tid * 49;                       // 1024*49 = 50176 >= 50000
  int s = 0;
  for (int i = 0; i < 49; ++i) { int idx = base + i; if (idx < NTGT) s += cnt[idx]; }
  part[tid] = s;
  __syncthreads();
  for (int off = 1; off < 1024; off <<= 1) {
    int v = (tid >= off) ? part[tid - off] : 0;
    __syncthreads();
    part[tid] += v;
    __syncthreads();
  }
  int run = (tid > 0) ? part[tid - 1] : 0;
  for (int i = 0; i < 49; ++i) {
    int idx = base + i;
    if (idx < NTGT) { rowstart[idx] = run; run += cnt[idx]; }
  }
  if (tid == 1023) rowstart[NTGT] = part[1023];
}

__global__ void k_pos(const int* __restrict__ tgt, const int* __restrict__ rowstart,
                      int* __restrict__ pos) {
  int e = blockIdx.x * 256 + threadIdx.x;
  if (e < NEDGE) pos[e] = rowstart[tgt[e]] + pos[e];   // pos aliases rank
}

// ---------- inverse permutation: order[pos[e]] = e ----------
__global__ void k_inv(const int* __restrict__ pos, int* __restrict__ order) {
  int e = blockIdx.x * 256 + threadIdx.x;
  if (e < NEDGE) order[pos[e]] = e;
}

// ---------- P = bf16(x_s @ W1a + b1), [NSRC][256] ----------
__global__ __launch_bounds__(256, 3) void k_pgemm(
    const float* __restrict__ xs, const u16* __restrict__ w1ap,
    const float* __restrict__ b1, u16* __restrict__ P) {
  __shared__ u16 At[64][136];    // 17408 B
  __shared__ u16 Ot[64][264];    // 33792 B
  const int tid = threadIdx.x;
  const int base = blockIdx.x * 64;
  {
    const int et = tid >> 2, p = tid & 3;
    const int row = base + et;
    u16* dst = &At[et][p * 32];
    if (row < NSRC) {
      const float4* f4 = (const float4*)(xs + (size_t)row * LDIM + p * 32);
#pragma unroll
      for (int i = 0; i < 4; ++i) {
        float4 a = f4[2 * i], b = f4[2 * i + 1];
        ushort8v pk = { f2bf(a.x), f2bf(a.y), f2bf(a.z), f2bf(a.w),
                        f2bf(b.x), f2bf(b.y), f2bf(b.z), f2bf(b.w) };
        *(ushort8v*)(dst + i * 8) = pk;
      }
    } else {
      ushort8v z = {0, 0, 0, 0, 0, 0, 0, 0};
#pragma unroll
      for (int i = 0; i < 4; ++i) *(ushort8v*)(dst + i * 8) = z;
    }
  }
  __syncthreads();

  const int lane = tid & 63, wid = tid >> 6;
  const int quad = lane >> 4, l16 = lane & 15;
  const int colb = wid * 64;
  const short8* __restrict__ wf = (const short8*)w1ap;

  f32x4 acc[4][4];
#pragma unroll
  for (int a = 0; a < 4; ++a)
#pragma unroll
    for (int b = 0; b < 4; ++b) acc[a][b] = (f32x4){0.f, 0.f, 0.f, 0.f};
#pragma unroll
  for (int kc = 0; kc < 4; ++kc) {
    short8 af[4], bfr[4];
#pragma unroll
    for (int ct = 0; ct < 4; ++ct)
      bfr[ct] = wf[(size_t)(kc * 16 + wid * 4 + ct) * 64 + lane];
#pragma unroll
    for (int rt = 0; rt < 4; ++rt)
      af[rt] = *(const short8*)&At[rt * 16 + l16][kc * 32 + quad * 8];
#pragma unroll
    for (int rt = 0; rt < 4; ++rt)
#pragma unroll
      for (int ct = 0; ct < 4; ++ct)
        acc[rt][ct] = MFMA(af[rt], bfr[ct], acc[rt][ct]);
  }
  // epilogue: + b1, store bf16 (NO activation: P is pre-activation partial)
#pragma unroll
  for (int ct = 0; ct < 4; ++ct) {
    int col = colb + ct * 16 + l16;
    float bias = b1[col];
#pragma unroll
    for (int rt = 0; rt < 4; ++rt)
#pragma unroll
      for (int r = 0; r < 4; ++r) {
        int row = rt * 16 + quad * 4 + r;
        Ot[row][col] = f2bf(acc[rt][ct][r] + bias);
      }
  }
  __syncthreads();
  {
    const int et = tid >> 2, p = tid & 3;
    const int row = base + et;
    if (row < NSRC) {
      u16* dst = P + (size_t)row * 256 + p * 64;
      const u16* sl = &Ot[et][p * 64];
#pragma unroll
      for (int i = 0; i < 8; ++i)
        *(ushort8v*)(dst + i * 8) = *(const ushort8v*)(sl + i * 8);
    }
  }
}

// ---------- edge (sorted order): t = leaky(P[src] + ea @ W1b), then in-block
// segment reduction over sorted targets -> f32 agg[NTGT][256]. No tbuf. ----------
__global__ __launch_bounds__(256, 3) void k_edge(
    const float* __restrict__ ea, const int* __restrict__ srcp,
    const int* __restrict__ tgtp, const int* __restrict__ order,
    const u16* __restrict__ Pg, const u16* __restrict__ w1bp,
    float* __restrict__ agg) {
  __shared__ u16 At[64][136];    // ea tile (sorted rows), 17408 B
  __shared__ u16 Pt[64][264];    // P gather, then t output, 33792 B
  __shared__ int s_tgt[64];
  const int tid = threadIdx.x;
  const int base = blockIdx.x * 64;   // sorted position base; NEDGE % 64 == 0

  // ---- stage: e = order[gp]; ea[e] -> At, P[src[e]] -> Pt, tgt[e] -> s_tgt ----
  {
    const int et = tid >> 2, p = tid & 3;
    const int e = order[base + et];
    if (p == 0) s_tgt[et] = tgtp[e];
    if (p < 2) {
      const float4* f4 = (const float4*)(ea + (size_t)e * LDIM + p * 64);
      u16* dst = &At[et][p * 64];
#pragma unroll
      for (int i = 0; i < 8; ++i) {
        float4 a = f4[2 * i], b = f4[2 * i + 1];
        ushort8v pk = { f2bf(a.x), f2bf(a.y), f2bf(a.z), f2bf(a.w),
                        f2bf(b.x), f2bf(b.y), f2bf(b.z), f2bf(b.w) };
        *(ushort8v*)(dst + i * 8) = pk;
      }
    } else {
      int sidx = srcp[e];
      const ushort8v* pr = (const ushort8v*)(Pg + (size_t)sidx * 256 + (p - 2) * 128);
      u16* dst = &Pt[et][(p - 2) * 128];
#pragma unroll
      for (int i = 0; i < 16; ++i) *(ushort8v*)(dst + i * 8) = pr[i];
    }
  }
  __syncthreads();

  const int lane = tid & 63, wid = tid >> 6;
  const int quad = lane >> 4, l16 = lane & 15;
  const int colb = wid * 64;
  const short8* __restrict__ wf = (const short8*)w1bp;

  f32x4 acc[4][4];
#pragma unroll
  for (int a = 0; a < 4; ++a)
#pragma unroll
    for (int b = 0; b < 4; ++b) acc[a][b] = (f32x4){0.f, 0.f, 0.f, 0.f};
#pragma unroll
  for (int kc = 0; kc < 4; ++kc) {
    short8 af[4], bfr[4];
#pragma unroll
    for (int ct = 0; ct < 4; ++ct)
      bfr[ct] = wf[(size_t)(kc * 16 + wid * 4 + ct) * 64 + lane];
#pragma unroll
    for (int rt = 0; rt < 4; ++rt)
      af[rt] = *(const short8*)&At[rt * 16 + l16][kc * 32 + quad * 8];
#pragma unroll
    for (int rt = 0; rt < 4; ++rt)
#pragma unroll
      for (int ct = 0; ct < 4; ++ct)
        acc[rt][ct] = MFMA(af[rt], bfr[ct], acc[rt][ct]);
  }
  // epilogue: + P (per wave's own column block), leaky, write t in-place (bf16)
#pragma unroll
  for (int ct = 0; ct < 4; ++ct) {
    int col = colb + ct * 16 + l16;
#pragma unroll
    for (int rt = 0; rt < 4; ++rt)
#pragma unroll
      for (int r = 0; r < 4; ++r) {
        int row = rt * 16 + quad * 4 + r;
        float v = acc[rt][ct][r] + bf2f(Pt[row][col]);
        v = v > 0.f ? v : SLOPE * v;
        Pt[row][col] = f2bf(v);
      }
  }
  __syncthreads();

  // ---- segment reduction: thread owns column `tid`; rows sorted by target.
  // Interior segments (start>0 and end<64) are complete -> plain store.
  // First/last segments may straddle block boundary -> atomicAdd (agg pre-zeroed).
  {
    const int col = tid;
    float accv = 0.f;
    int prev = s_tgt[0];
    int segstart = 0;
    for (int r = 0; r < 64; ++r) {
      int t = s_tgt[r];                 // uniform across block -> uniform branch
      if (t != prev) {
        float* dst = agg + (size_t)prev * 256 + col;
        if (segstart == 0) atomicAdd(dst, accv);
        else *dst = accv;
        accv = 0.f; prev = t; segstart = r;
      }
      accv += bf2f(Pt[r][col]);
    }
    atomicAdd(agg + (size_t)prev * 256 + col, accv);   // last segment: may straddle
  }
}

// ---------- node update: ain = [x_t | agg], K=384 GEMM1 with folded U1eff ----------
__global__ __launch_bounds__(256, 4) void k_node(
    const float* __restrict__ xt, const float* __restrict__ agg,
    const int* __restrict__ rowstart, const u16* __restrict__ u1e,
    const u16* __restrict__ u2p, const float* __restrict__ c1e,
    const float* __restrict__ vb, const float* __restrict__ c2,
    float* __restrict__ h2, float* __restrict__ stats) {
  __shared__ u16 ain[32][520];   // 33280 B
  __shared__ float sdeg[32];
  const int tid = threadIdx.x;
  const int lane = tid & 63, wid = tid >> 6;
  const int quad = lane >> 4, l16 = lane & 15;
  const int tbase = blockIdx.x * 32;

  // ---- stage: one wave per target slot; agg row is a single coalesced 1KB read ----
  for (int s = wid; s < 32; s += 4) {
    int t = tbase + s;
    if (t < NTGT) {
      if (lane < 32) {
        float4 v = ((const float4*)(xt + (size_t)t * LDIM))[lane];
        ushort4v p = { f2bf(v.x), f2bf(v.y), f2bf(v.z), f2bf(v.w) };
        *(ushort4v*)&ain[s][lane * 4] = p;
      }
      if (lane == 0) sdeg[s] = (float)(rowstart[t + 1] - rowstart[t]);
      float4 v = ((const float4*)(agg + (size_t)t * 256))[lane];   // 64 lanes x 16B
      ushort4v p = { f2bf(v.x), f2bf(v.y), f2bf(v.z), f2bf(v.w) };
      *(ushort4v*)&ain[s][128 + lane * 4] = p;
    } else {
      ushort8v z = {0, 0, 0, 0, 0, 0, 0, 0};
      *(ushort8v*)&ain[s][lane * 8] = z;
      if (lane == 0) sdeg[s] = 0.f;
    }
  }
  __syncthreads();

  const short8* __restrict__ u1f = (const short8*)u1e;
  const short8* __restrict__ u2f = (const short8*)u2p;

  // ---- GEMM1: h1 = leaky([x_t|T] @ U1eff + c1e + deg*vb), K=384, N=512 ----
  f32x4 acc[2][2][4];   // [half][rowtile][coltile]
#pragma unroll
  for (int h = 0; h < 2; ++h)
#pragma unroll
    for (int a = 0; a < 2; ++a)
#pragma unroll
      for (int b = 0; b < 4; ++b) acc[h][a][b] = (f32x4){0.f, 0.f, 0.f, 0.f};

#pragma unroll 2
  for (int kc = 0; kc < 12; ++kc) {
    short8 af[2];
#pragma unroll
    for (int rt = 0; rt < 2; ++rt)
      af[rt] = *(const short8*)&ain[rt * 16 + l16][kc * 32 + quad * 8];
#pragma unroll
    for (int h = 0; h < 2; ++h) {
      short8 bfr[4];
#pragma unroll
      for (int ct = 0; ct < 4; ++ct)
        bfr[ct] = u1f[(size_t)(kc * 32 + h * 16 + wid * 4 + ct) * 64 + lane];
#pragma unroll
      for (int rt = 0; rt < 2; ++rt)
#pragma unroll
        for (int ct = 0; ct < 4; ++ct)
          acc[h][rt][ct] = MFMA(af[rt], bfr[ct], acc[h][rt][ct]);
    }
  }
  __syncthreads();
  // epilogue 1 -> ain (h1, bf16)
#pragma unroll
  for (int h = 0; h < 2; ++h)
#pragma unroll
    for (int ct = 0; ct < 4; ++ct) {
      int col = h * 256 + wid * 64 + ct * 16 + l16;
      float cb = c1e[col], vbb = vb[col];
#pragma unroll
      for (int rt = 0; rt < 2; ++rt)
#pragma unroll
        for (int r = 0; r < 4; ++r) {
          int row = rt * 16 + quad * 4 + r;
          float v = acc[h][rt][ct][r] + cb + sdeg[row] * vbb;
          v = v > 0.f ? v : SLOPE * v;
          ain[row][col] = f2bf(v);
        }
    }
  __syncthreads();

  // ---- GEMM2: h2 = h1 @ U2 + c2, K=512, N=128 ----
  const int colb2 = wid * 32;
  f32x4 acc2[2][2];
#pragma unroll
  for (int a = 0; a < 2; ++a)
#pragma unroll
    for (int b = 0; b < 2; ++b) acc2[a][b] = (f32x4){0.f, 0.f, 0.f, 0.f};
#pragma unroll 4
  for (int kc = 0; kc < 16; ++kc) {
    short8 af[2], bfr[2];
#pragma unroll
    for (int ct = 0; ct < 2; ++ct)
      bfr[ct] = u2f[(size_t)(kc * 8 + wid * 2 + ct) * 64 + lane];
#pragma unroll
    for (int rt = 0; rt < 2; ++rt)
      af[rt] = *(const short8*)&ain[rt * 16 + l16][kc * 32 + quad * 8];
#pragma unroll
    for (int rt = 0; rt < 2; ++rt)
#pragma unroll
      for (int ct = 0; ct < 2; ++ct)
        acc2[rt][ct] = MFMA(af[rt], bfr[ct], acc2[rt][ct]);
  }
  // ---- epilogue 2: store h2 (f32) + BN partial sums ----
  float s1[2] = {0.f, 0.f}, s2[2] = {0.f, 0.f};
#pragma unroll
  for (int ct = 0; ct < 2; ++ct) {
    int col = colb2 + ct * 16 + l16;
    float cb = c2[col];
#pragma unroll
    for (int rt = 0; rt < 2; ++rt)
#pragma unroll
      for (int r = 0; r < 4; ++r) {
        int row = rt * 16 + quad * 4 + r;
        int t = tbase + row;
        if (t < NTGT) {
          float v = acc2[rt][ct][r] + cb;
          h2[(size_t)t * LDIM + col] = v;
          s1[ct] += v; s2[ct] += v * v;
        }
      }
  }
#pragma unroll
  for (int ct = 0; ct < 2; ++ct) {
    float a = s1[ct], b = s2[ct];
    a += __shfl_down(a, 32); b += __shfl_down(b, 32);
    a += __shfl_down(a, 16); b += __shfl_down(b, 16);
    if (lane < 16) {
      atomicAdd(&stats[colb2 + ct * 16 + l16], a);
      atomicAdd(&stats[128 + colb2 + ct * 16 + l16], b);
    }
  }
}

// ---------- BN finalize + apply ----------
__global__ void k_bnfin(const float* __restrict__ stats, const float* __restrict__ gamma,
                        const float* __restrict__ beta, float* __restrict__ ss) {
  int c = threadIdx.x;
  if (c < 128) {
    float mu = stats[c] * (1.0f / NTGT);
    float var = stats[128 + c] * (1.0f / NTGT) - mu * mu;
    float rs = rsqrtf(var + 1e-5f);
    float sc = gamma[c] * rs;
    ss[c] = sc;
    ss[128 + c] = beta[c] - mu * sc;
  }
}

__global__ void k_bnapply(const float* __restrict__ h2, const float* __restrict__ ss,
                          float* __restrict__ out) {
  int i = blockIdx.x * 256 + threadIdx.x;
  const int total = NTGT * LDIM / 4;
  const float4* h4 = (const float4*)h2;
  const float4* sc4 = (const float4*)ss;
  const float4* sh4 = (const float4*)(ss + 128);
  float4* o4 = (float4*)out;
  for (; i < total; i += gridDim.x * 256) {
    int cg = i & 31;
    float4 h = h4[i], sc = sc4[cg], sh = sh4[cg];
    float4 r = { h.x * sc.x + sh.x, h.y * sc.y + sh.y,
                 h.z * sc.z + sh.z, h.w * sc.w + sh.w };
    o4[i] = r;
  }
}

// ---------- launch ----------
extern "C" void kernel_launch(void* const* d_in, const int* in_sizes, int n_in,
                              void* d_out, int out_size, void* d_ws, size_t ws_size,
                              hipStream_t stream) {
  (void)in_sizes; (void)n_in; (void)out_size; (void)ws_size;
  const float* xs    = (const float*)d_in[0];
  const float* xt    = (const float*)d_in[1];
  const int*   ei    = (const int*)d_in[2];
  const float* ea    = (const float*)d_in[3];
  const float* xu    = (const float*)d_in[4];
  const float* W1    = (const float*)d_in[5];
  const float* b1    = (const float*)d_in[6];
  const float* W2    = (const float*)d_in[7];
  const float* b2    = (const float*)d_in[8];
  const float* U1    = (const float*)d_in[9];
  const float* c1    = (const float*)d_in[10];
  const float* U2    = (const float*)d_in[11];
  const float* c2    = (const float*)d_in[12];
  const float* gamma = (const float*)d_in[13];
  const float* beta  = (const float*)d_in[14];

  char* ws = (char*)d_ws;
  u16* w1a   = (u16*)(ws + 0x000000);     // 65536 B
  u16* w1b   = (u16*)(ws + 0x010000);     // 65536 B
  u16* u1e   = (u16*)(ws + 0x020000);     // 393216 B  (ends 0x80000)
  u16* u2p   = (u16*)(ws + 0x080000);     // 131072 B  (ends 0xA0000)
  float* w2b = (float*)(ws + 0x0A0000);   // 524288 B  (ends 0x120000)
  float* c1e = (float*)(ws + 0x120000);   // 2048 B
  float* vbv = (float*)(ws + 0x120800);   // 2048 B
  int* cnt   = (int*)(ws + 0x130000);     // 200000 B  (ends 0x160D40)
  int* rowst = (int*)(ws + 0x161000);     // 200004 B  (ends 0x191D44)
  int* pos   = (int*)(ws + 0x192000);     // 2560000 B (ends 0x403000)
  float* stats = (float*)(ws + 0x404000); // colsum[128] | colsq[128]  (1024 B)
  float* ss    = stats + 256;             // scale[128] | shift[128]   (1024 B)
  int* order = (int*)(ws + 0x405000);     // 2560000 B (ends 0x676000)
  float* agg = (float*)(ws + 0x680000);   // 51200000 B (ends 0x3754C00)
  // P (u16 [NSRC][256], 25.6 MB) aliases h2 (f32 [NTGT][128], 25.6 MB):
  // P is dead after k_edge; h2 first written by k_node (same stream, later).
  u16*   Pbuf = (u16*)(ws + 0x3760000);   // 25600000 B (ends 0x4FE9800)
  float* h2   = (float*)(ws + 0x3760000);

  const int* srcp = ei;
  const int* tgtp = ei + NEDGE;

  hipMemsetAsync(cnt, 0, NTGT * 4, stream);
  hipMemsetAsync(stats, 0, 256 * 4, stream);
  hipMemsetAsync(agg, 0, (size_t)NTGT * 256 * 4, stream);
  k_w2b<<<256, 256, 0, stream>>>(W2, U1, w2b);
  k_bias<<<1, 512, 0, stream>>>(U1, xu, b2, c1, c1e, vbv);
  k_prep<<<160, 256, 0, stream>>>(W1, U1, U2, w2b, w1a, w1b, u1e, u2p);
  k_count<<<2500, 256, 0, stream>>>(tgtp, cnt, pos);
  k_scan<<<1, 1024, 0, stream>>>(cnt, rowst);
  k_pos<<<2500, 256, 0, stream>>>(tgtp, rowst, pos);
  k_inv<<<2500, 256, 0, stream>>>(pos, order);
  k_pgemm<<<782, 256, 0, stream>>>(xs, w1a, b1, Pbuf);
  k_edge<<<10000, 256, 0, stream>>>(ea, srcp, tgtp, order, Pbuf, w1b, agg);
  k_node<<<1563, 256, 0, stream>>>(xt, agg, rowst, u1e, u2p, c1e, vbv, c2, h2, stats);
  k_bnfin<<<1, 128, 0, stream>>>(stats, gamma, beta, ss);
  k_bnapply<<<6250, 256, 0, stream>>>(h2, ss, (float*)d_out);
}